// Round 13
// baseline (195.570 us; speedup 1.0000x reference)
//
#include <hip/hip_runtime.h>

#define N_NODES 100000
#define N_EDGES 1600000
#define D 128
#define BM 64                     // rows per gemm block
#define GEMM_BLKS 1563            // ceil(100000/64)

// bucketed partition params (128-row buckets)
#define BROWS 128
#define NB 782                    // ceil(100000/128)
#define EB 250                    // edge blocks
#define EPB 6400                  // edges per block
#define NTAB (NB * EB)            // 195500
#define SCAN_BLKS 191             // ceil(NTAB/1024)

#define CHUNK 4096                // LDS record staging per pass (max bucket ~2.2k)

typedef __attribute__((ext_vector_type(8))) short short8_t;
typedef __attribute__((ext_vector_type(4))) float float4_t;
typedef __attribute__((ext_vector_type(2))) float f32x2_t;

__device__ __forceinline__ unsigned pack_bf16x2(float a, float b) {
    unsigned ua = __float_as_uint(a);
    unsigned ub = __float_as_uint(b);
    ua = (ua + 0x7fffu + ((ua >> 16) & 1u)) >> 16;
    ub = (ub + 0x7fffu + ((ub >> 16) & 1u)) & 0xffff0000u;
    return ua | ub;
}

__device__ __forceinline__ float selu_f(float x) {
    const float SCALE = 1.0507009873554805f;
    const float ALPHA = 1.6732632423543772f;
    return x > 0.f ? SCALE * x : SCALE * ALPHA * (expf(x) - 1.f);
}

// ---------------- K1: bhist (blocks 0..249)  ∪  prep_w (blocks 250..253) ----
__global__ __launch_bounds__(256) void bhist_prep_kernel(
    const int* __restrict__ erow, const float* __restrict__ W,
    unsigned* __restrict__ tbl, unsigned short* __restrict__ wt)
{
    __shared__ unsigned hcnt[NB];
    const int t = threadIdx.x;
    if (blockIdx.x < EB) {
        const int k = blockIdx.x;
        for (int i = t; i < NB; i += 256) hcnt[i] = 0;
        __syncthreads();
        const int4* q = (const int4*)(erow + k * EPB);
        for (int i = t; i < EPB / 4; i += 256) {
            const int4 r = q[i];
            atomicAdd(&hcnt[r.x >> 7], 1u);
            atomicAdd(&hcnt[r.y >> 7], 1u);
            atomicAdd(&hcnt[r.z >> 7], 1u);
            atomicAdd(&hcnt[r.w >> 7], 1u);
        }
        __syncthreads();
        for (int i = t; i < NB; i += 256) tbl[k * NB + i] = hcnt[i];
    } else {
        // W fp32 [k][n] -> bf16 W^T [n][k]; 4 blocks x 4096 elems
        const int pb = blockIdx.x - EB;
        for (int idx = pb * 4096 + t; idx < (pb + 1) * 4096; idx += 256) {
            const int k = idx >> 7, n = idx & 127;
            unsigned u = __float_as_uint(W[idx]);
            u = (u + 0x7fffu + ((u >> 16) & 1u)) >> 16;
            wt[n * D + k] = (unsigned short)u;
        }
    }
}

// ---------------- K2: local scan (writes lex + raw per-chunk totals bsum) ----
__global__ __launch_bounds__(1024) void scan_local_kernel(
    const unsigned* __restrict__ tbl, unsigned* __restrict__ lex,
    unsigned* __restrict__ bsum)
{
    __shared__ unsigned wsum[16];
    const int t = threadIdx.x;
    const int L = blockIdx.x * 1024 + t;
    const int lane = t & 63;

    unsigned v = 0;
    if (L < NTAB) {
        const int b = L / EB;
        const int k = L - b * EB;
        v = tbl[k * NB + b];
    }
    unsigned x = v;
#pragma unroll
    for (int d = 1; d < 64; d <<= 1) {
        const unsigned y = __shfl_up(x, d, 64);
        if (lane >= d) x += y;
    }
    if (lane == 63) wsum[t >> 6] = x;
    __syncthreads();
    unsigned add = 0;
    for (int w = 0; w < (t >> 6); ++w) add += wsum[w];
    x += add;
    if (L < NTAB) lex[L] = x - v;
    if (t == 1023) bsum[blockIdx.x] = x;   // raw per-chunk total (not scanned)
}

// ---------------- K3: bscatter (blocks 0..249) ∪ gemm (250..1812) ------------
// bscatter (needs lex/bsum) and gemm (needs wt/feat) are data-independent, so
// bscatter's latency-bound scatter hides under gemm's BW/MFMA work.
__global__ __launch_bounds__(256) void bscatter_gemm_kernel(
    const int* __restrict__ erow, const int* __restrict__ ecol,
    const float* __restrict__ eval_, const unsigned* __restrict__ lex,
    const unsigned* __restrict__ bsum, unsigned* __restrict__ tbl,
    int2* __restrict__ rec,
    const float* __restrict__ feat, const unsigned short* __restrict__ wt,
    unsigned* __restrict__ h16)
{
    __shared__ __align__(16) char smem[52224];
    const int t = threadIdx.x;

    if (blockIdx.x < EB) {
        // ---- bscatter with inline scan-apply ----
        unsigned* bp   = (unsigned*)smem;        // [192]
        unsigned* wtot = bp + 192;               // [4]
        unsigned* base = wtot + 4;               // [NB]
        unsigned* rk   = base + NB;              // [NB]
        const int k = blockIdx.x;

        unsigned v = 0, x = 0;
        if (t < 192) {
            v = (t < SCAN_BLKS) ? bsum[t] : 0u;
            x = v;
#pragma unroll
            for (int d = 1; d < 64; d <<= 1) {
                const unsigned y = __shfl_up(x, d, 64);
                if ((t & 63) >= d) x += y;
            }
            if ((t & 63) == 63) wtot[t >> 6] = x;
        }
        __syncthreads();
        if (t < 192) {
            unsigned add = 0;
            if (t >= 64)  add += wtot[0];
            if (t >= 128) add += wtot[1];
            bp[t] = x - v + add;            // exclusive chunk prefix
        }
        __syncthreads();

        for (int b = t; b < NB; b += 256) {
            const int L = b * EB + k;
            const unsigned bs_ = lex[L] + bp[L >> 10];
            base[b] = bs_;
            rk[b] = 0;
            if (k == 0) tbl[b] = bs_;       // bucket starts for K4
        }
        __syncthreads();

        const int4*   qr = (const int4*)(erow + k * EPB);
        const int4*   qc = (const int4*)(ecol + k * EPB);
        const float4* qv = (const float4*)(eval_ + k * EPB);

        for (int i = t; i < EPB / 4; i += 256) {
            const int4   r = qr[i];
            const int4   c = qc[i];
            const float4 vv = qv[i];
            {
                const int b = r.x >> 7;
                const unsigned pos = base[b] + atomicAdd(&rk[b], 1u);
                rec[pos] = make_int2(c.x | ((r.x & 127) << 17), __float_as_int(vv.x));
            }
            {
                const int b = r.y >> 7;
                const unsigned pos = base[b] + atomicAdd(&rk[b], 1u);
                rec[pos] = make_int2(c.y | ((r.y & 127) << 17), __float_as_int(vv.y));
            }
            {
                const int b = r.z >> 7;
                const unsigned pos = base[b] + atomicAdd(&rk[b], 1u);
                rec[pos] = make_int2(c.z | ((r.z & 127) << 17), __float_as_int(vv.z));
            }
            {
                const int b = r.w >> 7;
                const unsigned pos = base[b] + atomicAdd(&rk[b], 1u);
                rec[pos] = make_int2(c.w | ((r.w & 127) << 17), __float_as_int(vv.w));
            }
        }
    } else {
        // ---- gemm (R4-proven MFMA tile) ----
        short* At = (short*)smem;             // [64][136]
        short* Wt = (short*)(smem + 17408);   // [128][136]
        const int g = blockIdx.x - EB;
        const int rowBase = g * BM;

        {   // stage W^T bf16
            const int n = t >> 1, hf = t & 1;
            const uint4* src = (const uint4*)(wt + n * D + hf * 64);
            uint4* dst = (uint4*)&Wt[n * 136 + hf * 64];
#pragma unroll
            for (int j = 0; j < 8; ++j) dst[j] = src[j];
        }
        {   // stage A tile fp32->bf16
#pragma unroll
            for (int i = 0; i < 8; ++i) {
                const int p = t + 256 * i;
                const int r = p >> 5, kq = p & 31;
                int row = rowBase + r;
                if (row >= N_NODES) row = N_NODES - 1;
                const float4 f = *(const float4*)&feat[(size_t)row * D + kq * 4];
                uint2 u;
                u.x = pack_bf16x2(f.x, f.y);
                u.y = pack_bf16x2(f.z, f.w);
                *(uint2*)&At[r * 136 + kq * 4] = u;
            }
        }
        __syncthreads();

        const int w = t >> 6, lane = t & 63;
        const int m16 = lane & 15, kg = lane >> 4;

        short8_t a_frag[4];
        const int arow = w * 16 + m16;
#pragma unroll
        for (int k0 = 0; k0 < 4; ++k0)
            a_frag[k0] = *(const short8_t*)&At[arow * 136 + k0 * 32 + kg * 8];

#pragma unroll
        for (int nt = 0; nt < 8; ++nt) {
            float4_t acc = {0.f, 0.f, 0.f, 0.f};
#pragma unroll
            for (int k0 = 0; k0 < 4; ++k0) {
                const short8_t b =
                    *(const short8_t*)&Wt[(nt * 16 + m16) * 136 + k0 * 32 + kg * 8];
                acc = __builtin_amdgcn_mfma_f32_16x16x32_bf16(a_frag[k0], b, acc, 0, 0, 0);
            }
            float mine[4], part[4];
#pragma unroll
            for (int i = 0; i < 4; ++i) {
                mine[i] = acc[i];
                part[i] = __shfl_xor(mine[i], 1, 64);
            }
            if ((m16 & 1) == 0) {
                const int cp = (nt * 16 + m16) >> 1;
#pragma unroll
                for (int i = 0; i < 4; ++i) {
                    const int row = rowBase + w * 16 + kg * 4 + i;
                    if (row < N_NODES)
                        h16[(size_t)row * 64 + cp] = pack_bf16x2(mine[i], part[i]);
                }
            }
        }
    }
}

// ---------------- K4: fused bsort + spmm (one block per 128-row bucket) ------
// Sort the bucket's records into LDS (integer LDS atomics — the proven-fast
// path used by bhist/bsort all session), then 8 waves x 16 rows each run the
// proven v4 gather loop with records read from LDS. Deletes rec2 (25.6 MB
// HBM roundtrip) and overlaps sort work with gather stalls. Chunked staging
// (CHUNK=4096 > max bucket ~2.2k) keeps it correct for any distribution.
__global__ __launch_bounds__(512) void bsort_spmm_kernel(
    const unsigned* __restrict__ tbl, const int2* __restrict__ rec,
    const unsigned* __restrict__ h16, const float* __restrict__ skip,
    const float* __restrict__ bias, float* __restrict__ out)
{
    __shared__ unsigned cnt[BROWS], base_[BROWS], rk[BROWS];
    __shared__ unsigned w0tot;
    __shared__ __align__(16) int2 srec[CHUNK];     // 32 KB

    const int t = threadIdx.x;        // 0..511
    const int lane = t & 63;
    const int w = t >> 6;             // wave 0..7
    const int b = blockIdx.x;
    const int rowBase = b * BROWS;

    const unsigned s = tbl[b];
    const unsigned e = (b == NB - 1) ? (unsigned)N_EDGES : tbl[b + 1];

    const int c2 = lane * 2;
    const float2 sk = *(const float2*)&skip[c2];
    const float2 bs = *(const float2*)&bias[c2];

    float accx[16], accy[16];
#pragma unroll
    for (int r = 0; r < 16; ++r) { accx[r] = 0.f; accy[r] = 0.f; }

    for (unsigned cs = s; cs < e; cs += CHUNK) {
        const unsigned ce = (cs + CHUNK < e) ? cs + CHUNK : e;

        if (t < BROWS) { cnt[t] = 0; rk[t] = 0; }
        __syncthreads();

        // load records (once) + LDS histogram
        int2 lr[8];
#pragma unroll
        for (int j = 0; j < 8; ++j) {
            const unsigned i = cs + (unsigned)t + 512u * (unsigned)j;
            if (i < ce) {
                lr[j] = rec[i];
                atomicAdd(&cnt[(lr[j].x >> 17) & 127], 1u);
            }
        }
        __syncthreads();

        // exclusive scan of cnt[128] (2 waves)
        unsigned v = 0, x = 0;
        if (t < BROWS) {
            v = cnt[t]; x = v;
#pragma unroll
            for (int d = 1; d < 64; d <<= 1) {
                const unsigned y = __shfl_up(x, d, 64);
                if ((t & 63) >= d) x += y;
            }
        }
        if (t == 63) w0tot = x;
        __syncthreads();
        if (t < BROWS) base_[t] = x - v + ((t >= 64) ? w0tot : 0u);
        __syncthreads();

        // scatter into LDS, row-sorted
#pragma unroll
        for (int j = 0; j < 8; ++j) {
            const unsigned i = cs + (unsigned)t + 512u * (unsigned)j;
            if (i < ce) {
                const int rl = (lr[j].x >> 17) & 127;
                srec[base_[rl] + atomicAdd(&rk[rl], 1u)] = lr[j];
            }
        }
        __syncthreads();

        // spmm: wave w processes local rows w*16 .. w*16+15 (fully unrolled
        // so accx/accy indices stay compile-time — no scratch)
#pragma unroll
        for (int r = 0; r < 16; ++r) {
            const int rl = w * 16 + r;
            const unsigned ls = base_[rl];
            const unsigned le = ls + rk[rl];

            float ax = 0.f, ay = 0.f, bx = 0.f, by = 0.f;
            for (unsigned j = ls; j < le; j += 8) {
                int2     E[8];
                unsigned g[8];
                float    vv[8];
#pragma unroll
                for (int k = 0; k < 8; ++k) {
                    const unsigned idx = j + (unsigned)k;
                    E[k] = srec[idx < le ? idx : le - 1u];
                    vv[k] = (idx < le) ? __int_as_float(E[k].y) : 0.f;
                }
#pragma unroll
                for (int k = 0; k < 8; ++k)
                    g[k] = h16[(size_t)(((unsigned)E[k].x) & 0x1FFFFu) * 64 + lane];
#pragma unroll
                for (int k = 0; k < 8; ++k) {
                    if (k & 1) {
                        bx = fmaf(vv[k], __uint_as_float(g[k] << 16), bx);
                        by = fmaf(vv[k], __uint_as_float(g[k] & 0xffff0000u), by);
                    } else {
                        ax = fmaf(vv[k], __uint_as_float(g[k] << 16), ax);
                        ay = fmaf(vv[k], __uint_as_float(g[k] & 0xffff0000u), ay);
                    }
                }
            }
            accx[r] += ax + bx;
            accy[r] += ay + by;
        }
        __syncthreads();   // before next chunk reuses LDS
    }

    // epilogue: out = selu(h*skip + Ah + bias); lane owns cols (c2, c2+1)
#pragma unroll
    for (int r = 0; r < 16; ++r) {
        const int row = rowBase + w * 16 + r;
        if (row < N_NODES) {
            const unsigned hw = h16[(size_t)row * 64 + lane];
            float ox = fmaf(__uint_as_float(hw << 16),         sk.x, accx[r] + bs.x);
            float oy = fmaf(__uint_as_float(hw & 0xffff0000u), sk.y, accy[r] + bs.y);
            f32x2_t o;
            o.x = selu_f(ox);
            o.y = selu_f(oy);
            __builtin_nontemporal_store(o, (f32x2_t*)&out[(size_t)row * D + c2]);
        }
    }
}

// ---------------- Fallback path (atomic COO, all fp32) -----------------------
__global__ __launch_bounds__(256) void gemm_fb_kernel(
    const float* __restrict__ feat, const float* __restrict__ W,
    const float* __restrict__ bias, const float* __restrict__ skip,
    float* __restrict__ h, float* __restrict__ out)
{
    __shared__ float Wl[D * D];
    __shared__ float Fl[32 * D];
    const int tid = threadIdx.x;

    const float4* W4 = (const float4*)W;
    float4* Wl4 = (float4*)Wl;
#pragma unroll
    for (int i = 0; i < 16; ++i) Wl4[tid + 256 * i] = W4[tid + 256 * i];

    const size_t rowBase = (size_t)blockIdx.x * 32;
    const float4* F4 = (const float4*)(feat + rowBase * D);
    float4* Fl4 = (float4*)Fl;
#pragma unroll
    for (int i = 0; i < 4; ++i) Fl4[tid + 256 * i] = F4[tid + 256 * i];
    __syncthreads();

    const int colg = (tid & 31) * 4;
    const int row0 = (tid >> 5) * 4;
    float4 acc[4];
#pragma unroll
    for (int r = 0; r < 4; ++r) acc[r] = make_float4(0.f, 0.f, 0.f, 0.f);
#pragma unroll 4
    for (int k = 0; k < D; ++k) {
        const float4 w = *(const float4*)&Wl[k * D + colg];
#pragma unroll
        for (int r = 0; r < 4; ++r) {
            const float aa = Fl[(row0 + r) * D + k];
            acc[r].x += aa * w.x; acc[r].y += aa * w.y;
            acc[r].z += aa * w.z; acc[r].w += aa * w.w;
        }
    }
    const float4 sk = *(const float4*)&skip[colg];
    const float4 bs = *(const float4*)&bias[colg];
#pragma unroll
    for (int r = 0; r < 4; ++r) {
        const size_t row = rowBase + row0 + r;
        *(float4*)&h[row * D + colg] = acc[r];
        float4 o;
        o.x = acc[r].x * sk.x + bs.x; o.y = acc[r].y * sk.y + bs.y;
        o.z = acc[r].z * sk.z + bs.z; o.w = acc[r].w * sk.w + bs.w;
        *(float4*)&out[row * D + colg] = o;
    }
}

__global__ __launch_bounds__(256) void spmm_atomic_kernel(
    const int* __restrict__ erow, const int* __restrict__ ecol,
    const float* __restrict__ eval_, const float* __restrict__ h,
    float* __restrict__ out)
{
    const int e = blockIdx.x * 4 + (threadIdx.x >> 6);
    if (e >= N_EDGES) return;
    const int lane = threadIdx.x & 63;
    const int r = erow[e];
    const int c = ecol[e];
    const float v = eval_[e];
    const float2 hv = *(const float2*)&h[(size_t)c * D + lane * 2];
    float* o = &out[(size_t)r * D + lane * 2];
    atomicAdd(o + 0, v * hv.x);
    atomicAdd(o + 1, v * hv.y);
}

__global__ __launch_bounds__(256) void selu_kernel(float* __restrict__ out)
{
    const size_t i = (size_t)blockIdx.x * blockDim.x + threadIdx.x;
    float4 v = ((float4*)out)[i];
    v.x = selu_f(v.x); v.y = selu_f(v.y); v.z = selu_f(v.z); v.w = selu_f(v.w);
    ((float4*)out)[i] = v;
}

extern "C" void kernel_launch(void* const* d_in, const int* in_sizes, int n_in,
                              void* d_out, int out_size, void* d_ws, size_t ws_size,
                              hipStream_t stream)
{
    const float* feat  = (const float*)d_in[0];
    const int*   erow  = (const int*)d_in[1];
    const int*   ecol  = (const int*)d_in[2];
    const float* eval_ = (const float*)d_in[3];
    const float* W     = (const float*)d_in[4];
    const float* bias  = (const float*)d_in[5];
    const float* skip  = (const float*)d_in[6];

    float* out = (float*)d_out;

    // fast-path workspace layout (bytes)
    const size_t off_h16  = 0;            // 25,600,000
    const size_t off_tbl  = 25600000;     //    782,000
    const size_t off_lex  = 26382000;     //    782,336
    const size_t off_bs   = 27164336;     //      1,024
    const size_t off_rst  = 27165360;     //    400,000 (unused)
    const size_t off_wt   = 27565360;     //     32,768
    const size_t off_rec  = 27598128;     // 12,800,000
    const size_t off_rec2 = 40398128;     // 12,800,000 (unused)
    const size_t needed   = 53198128;
    (void)off_rst; (void)off_rec2;

    char* ws = (char*)d_ws;
    unsigned*       h16    = (unsigned*)(ws + off_h16);
    unsigned*       tbl    = (unsigned*)(ws + off_tbl);
    unsigned*       lex    = (unsigned*)(ws + off_lex);
    unsigned*       bsum   = (unsigned*)(ws + off_bs);
    unsigned short* wt     = (unsigned short*)(ws + off_wt);
    int2*           rec    = (int2*)(ws + off_rec);

    if (ws_size >= needed) {
        bhist_prep_kernel<<<EB + 4, 256, 0, stream>>>(erow, W, tbl, wt);
        scan_local_kernel<<<SCAN_BLKS, 1024, 0, stream>>>(tbl, lex, bsum);
        bscatter_gemm_kernel<<<EB + GEMM_BLKS, 256, 0, stream>>>(
            erow, ecol, eval_, lex, bsum, tbl, rec, feat, wt, h16);
        bsort_spmm_kernel<<<NB, 512, 0, stream>>>(
            tbl, rec, h16, skip, bias, out);
    } else {
        float* h = (float*)d_ws;
        gemm_fb_kernel<<<N_NODES / 32, 256, 0, stream>>>(feat, W, bias, skip, h, out);
        spmm_atomic_kernel<<<N_EDGES / 4, 256, 0, stream>>>(erow, ecol, eval_, h, out);
        selu_kernel<<<(N_NODES * D) / (256 * 4), 256, 0, stream>>>(out);
    }
}

// Round 14
// 125.510 us; speedup vs baseline: 1.5582x; 1.5582x over previous
//
#include <hip/hip_runtime.h>

#define N_NODES 100000
#define N_EDGES 1600000
#define D 128
#define BM 64                     // rows per gemm block
#define GEMM_BLKS 1563            // ceil(100000/64)

// bucketed partition params (128-row buckets — the R4-proven config)
#define BROWS 128
#define NB 782                    // ceil(100000/128)
#define EB 250                    // edge blocks
#define EPB 6400                  // edges per block
#define NTAB (NB * EB)            // 195500
#define SCAN_BLKS 191             // ceil(NTAB/1024)

// spmm: 4 waves/block, 4 rows/wave -> 16 rows/block
#define SPMM_BLKS 6250            // 100000 / 16

typedef __attribute__((ext_vector_type(8))) short short8_t;
typedef __attribute__((ext_vector_type(4))) float float4_t;
typedef __attribute__((ext_vector_type(2))) float f32x2_t;

__device__ __forceinline__ unsigned pack_bf16x2(float a, float b) {
    unsigned ua = __float_as_uint(a);
    unsigned ub = __float_as_uint(b);
    ua = (ua + 0x7fffu + ((ua >> 16) & 1u)) >> 16;
    ub = (ub + 0x7fffu + ((ub >> 16) & 1u)) & 0xffff0000u;
    return ua | ub;
}

__device__ __forceinline__ float selu_f(float x) {
    const float SCALE = 1.0507009873554805f;
    const float ALPHA = 1.6732632423543772f;
    return x > 0.f ? SCALE * x : SCALE * ALPHA * (expf(x) - 1.f);
}

// ---------------- K1: bhist (blocks 0..249)  ∪  prep_w (blocks 250..253) ----
__global__ __launch_bounds__(256) void bhist_prep_kernel(
    const int* __restrict__ erow, const float* __restrict__ W,
    unsigned* __restrict__ tbl, unsigned short* __restrict__ wt)
{
    __shared__ unsigned hcnt[NB];
    const int t = threadIdx.x;
    if (blockIdx.x < EB) {
        const int k = blockIdx.x;
        for (int i = t; i < NB; i += 256) hcnt[i] = 0;
        __syncthreads();
        const int4* q = (const int4*)(erow + k * EPB);
        for (int i = t; i < EPB / 4; i += 256) {
            const int4 r = q[i];
            atomicAdd(&hcnt[r.x >> 7], 1u);
            atomicAdd(&hcnt[r.y >> 7], 1u);
            atomicAdd(&hcnt[r.z >> 7], 1u);
            atomicAdd(&hcnt[r.w >> 7], 1u);
        }
        __syncthreads();
        for (int i = t; i < NB; i += 256) tbl[k * NB + i] = hcnt[i];
    } else {
        // W fp32 [k][n] -> bf16 W^T [n][k]; 4 blocks x 4096 elems
        const int pb = blockIdx.x - EB;
        for (int idx = pb * 4096 + t; idx < (pb + 1) * 4096; idx += 256) {
            const int k = idx >> 7, n = idx & 127;
            unsigned u = __float_as_uint(W[idx]);
            u = (u + 0x7fffu + ((u >> 16) & 1u)) >> 16;
            wt[n * D + k] = (unsigned short)u;
        }
    }
}

// ---------------- K2: local scan (writes lex + raw per-chunk totals bsum) ----
__global__ __launch_bounds__(1024) void scan_local_kernel(
    const unsigned* __restrict__ tbl, unsigned* __restrict__ lex,
    unsigned* __restrict__ bsum)
{
    __shared__ unsigned wsum[16];
    const int t = threadIdx.x;
    const int L = blockIdx.x * 1024 + t;
    const int lane = t & 63;

    unsigned v = 0;
    if (L < NTAB) {
        const int b = L / EB;
        const int k = L - b * EB;
        v = tbl[k * NB + b];
    }
    unsigned x = v;
#pragma unroll
    for (int d = 1; d < 64; d <<= 1) {
        const unsigned y = __shfl_up(x, d, 64);
        if (lane >= d) x += y;
    }
    if (lane == 63) wsum[t >> 6] = x;
    __syncthreads();
    unsigned add = 0;
    for (int w = 0; w < (t >> 6); ++w) add += wsum[w];
    x += add;
    if (L < NTAB) lex[L] = x - v;
    if (t == 1023) bsum[blockIdx.x] = x;   // raw per-chunk total (not scanned)
}

// ---------------- K3: bscatter with inline scan-apply ------------------------
__global__ __launch_bounds__(256) void bscatter_kernel(
    const int* __restrict__ erow, const int* __restrict__ ecol,
    const float* __restrict__ eval_, const unsigned* __restrict__ lex,
    const unsigned* __restrict__ bsum, unsigned* __restrict__ tbl,
    int2* __restrict__ rec)
{
    __shared__ unsigned bp[192];
    __shared__ unsigned wtot[4];
    __shared__ unsigned base[NB], rk[NB];
    const int t = threadIdx.x;
    const int k = blockIdx.x;

    // exclusive prefix of the 191 chunk totals (3 waves participate)
    unsigned v = 0, x = 0;
    if (t < 192) {
        v = (t < SCAN_BLKS) ? bsum[t] : 0u;
        x = v;
#pragma unroll
        for (int d = 1; d < 64; d <<= 1) {
            const unsigned y = __shfl_up(x, d, 64);
            if ((t & 63) >= d) x += y;
        }
        if ((t & 63) == 63) wtot[t >> 6] = x;
    }
    __syncthreads();
    if (t < 192) {
        unsigned add = 0;
        if (t >= 64)  add += wtot[0];
        if (t >= 128) add += wtot[1];
        bp[t] = x - v + add;            // exclusive chunk prefix
    }
    __syncthreads();

    for (int b = t; b < NB; b += 256) {
        const int L = b * EB + k;
        const unsigned bs_ = lex[L] + bp[L >> 10];
        base[b] = bs_;
        rk[b] = 0;
        if (k == 0) tbl[b] = bs_;       // bucket starts for K4's bsort
    }
    __syncthreads();

    const int4*   qr = (const int4*)(erow + k * EPB);
    const int4*   qc = (const int4*)(ecol + k * EPB);
    const float4* qv = (const float4*)(eval_ + k * EPB);

    for (int i = t; i < EPB / 4; i += 256) {
        const int4   r = qr[i];
        const int4   c = qc[i];
        const float4 vv = qv[i];
        {
            const int b = r.x >> 7;
            const unsigned pos = base[b] + atomicAdd(&rk[b], 1u);
            rec[pos] = make_int2(c.x | ((r.x & 127) << 17), __float_as_int(vv.x));
        }
        {
            const int b = r.y >> 7;
            const unsigned pos = base[b] + atomicAdd(&rk[b], 1u);
            rec[pos] = make_int2(c.y | ((r.y & 127) << 17), __float_as_int(vv.y));
        }
        {
            const int b = r.z >> 7;
            const unsigned pos = base[b] + atomicAdd(&rk[b], 1u);
            rec[pos] = make_int2(c.z | ((r.z & 127) << 17), __float_as_int(vv.z));
        }
        {
            const int b = r.w >> 7;
            const unsigned pos = base[b] + atomicAdd(&rk[b], 1u);
            rec[pos] = make_int2(c.w | ((r.w & 127) << 17), __float_as_int(vv.w));
        }
    }
}

// ---------------- K4: gemm (blocks 0..1562) ∪ bsort (1563..2344) -------------
__global__ __launch_bounds__(256) void gemm_bsort_kernel(
    const float* __restrict__ feat, const unsigned short* __restrict__ wt,
    unsigned* __restrict__ h16,
    const unsigned* __restrict__ tbl, const int2* __restrict__ rec,
    int2* __restrict__ rec2, unsigned* __restrict__ rstart)
{
    __shared__ __align__(16) char smem[52224];
    const int t = threadIdx.x;

    if (blockIdx.x < GEMM_BLKS) {
        short* At = (short*)smem;             // [64][136]
        short* Wt = (short*)(smem + 17408);   // [128][136]
        const int rowBase = blockIdx.x * BM;

        {   // stage W^T bf16
            const int n = t >> 1, hf = t & 1;
            const uint4* src = (const uint4*)(wt + n * D + hf * 64);
            uint4* dst = (uint4*)&Wt[n * 136 + hf * 64];
#pragma unroll
            for (int j = 0; j < 8; ++j) dst[j] = src[j];
        }
        {   // stage A tile fp32->bf16
#pragma unroll
            for (int i = 0; i < 8; ++i) {
                const int p = t + 256 * i;
                const int r = p >> 5, kq = p & 31;
                int row = rowBase + r;
                if (row >= N_NODES) row = N_NODES - 1;
                const float4 f = *(const float4*)&feat[(size_t)row * D + kq * 4];
                uint2 u;
                u.x = pack_bf16x2(f.x, f.y);
                u.y = pack_bf16x2(f.z, f.w);
                *(uint2*)&At[r * 136 + kq * 4] = u;
            }
        }
        __syncthreads();

        const int w = t >> 6, lane = t & 63;
        const int m16 = lane & 15, kg = lane >> 4;

        short8_t a_frag[4];
        const int arow = w * 16 + m16;
#pragma unroll
        for (int k0 = 0; k0 < 4; ++k0)
            a_frag[k0] = *(const short8_t*)&At[arow * 136 + k0 * 32 + kg * 8];

#pragma unroll
        for (int nt = 0; nt < 8; ++nt) {
            float4_t acc = {0.f, 0.f, 0.f, 0.f};
#pragma unroll
            for (int k0 = 0; k0 < 4; ++k0) {
                const short8_t b =
                    *(const short8_t*)&Wt[(nt * 16 + m16) * 136 + k0 * 32 + kg * 8];
                acc = __builtin_amdgcn_mfma_f32_16x16x32_bf16(a_frag[k0], b, acc, 0, 0, 0);
            }
            float mine[4], part[4];
#pragma unroll
            for (int i = 0; i < 4; ++i) {
                mine[i] = acc[i];
                part[i] = __shfl_xor(mine[i], 1, 64);
            }
            if ((m16 & 1) == 0) {
                const int cp = (nt * 16 + m16) >> 1;
#pragma unroll
                for (int i = 0; i < 4; ++i) {
                    const int row = rowBase + w * 16 + kg * 4 + i;
                    if (row < N_NODES)
                        h16[(size_t)row * 64 + cp] = pack_bf16x2(mine[i], part[i]);
                }
            }
        }
    } else {
        // ---- bsort: sort bucket b's records by row-within-bucket ----
        unsigned* cnt  = (unsigned*)smem;       // [128]
        unsigned* bas  = cnt + BROWS;           // [128]
        unsigned* rk   = bas + BROWS;           // [128]
        unsigned* w0p  = rk + BROWS;            // [1]
        const int b = blockIdx.x - GEMM_BLKS;

        if (t < BROWS) { cnt[t] = 0; rk[t] = 0; }
        __syncthreads();

        const unsigned s = tbl[b];
        const unsigned e = (b == NB - 1) ? (unsigned)N_EDGES : tbl[b + 1];

        for (unsigned j = s + t; j < e; j += 256)
            atomicAdd(&cnt[(rec[j].x >> 17) & 127], 1u);
        __syncthreads();

        unsigned v = 0, x = 0;
        if (t < BROWS) {
            v = cnt[t]; x = v;
#pragma unroll
            for (int d = 1; d < 64; d <<= 1) {
                const unsigned y = __shfl_up(x, d, 64);
                if ((t & 63) >= d) x += y;
            }
        }
        if (t == 63) w0p[0] = x;
        __syncthreads();
        if (t < BROWS) {
            const unsigned ex = x - v + ((t >= 64) ? w0p[0] : 0u);
            bas[t] = s + ex;
            const int row = b * BROWS + t;
            if (row < N_NODES) rstart[row] = s + ex;
        }
        __syncthreads();

        for (unsigned j = s + t; j < e; j += 256) {
            const int2 R = rec[j];
            const int rl = (R.x >> 17) & 127;
            const unsigned pos = bas[rl] + atomicAdd(&rk[rl], 1u);
            rec2[pos] = R;
        }
    }
}

// ---------------- K5: spmm (R4-proven register CSR, pipelined, nt-stores) ----
__global__ __launch_bounds__(256) void spmm_csr_kernel(
    const unsigned* __restrict__ rstart, const int2* __restrict__ rec,
    const unsigned* __restrict__ h16, const float* __restrict__ skip,
    const float* __restrict__ bias, float* __restrict__ out)
{
    const int lane = threadIdx.x & 63;
    const int wid  = threadIdx.x >> 6;
    const int rowBase = (blockIdx.x * 4 + wid) * 4;   // 4 rows per wave

    const int c2 = lane * 2;
    const float2 sk = *(const float2*)&skip[c2];
    const float2 bs = *(const float2*)&bias[c2];

    // row segment bounds: rows are contiguous, so 5 loads cover 4 rows
    unsigned sb[5];
#pragma unroll
    for (int i = 0; i < 5; ++i) {
        const int rr = rowBase + i;
        const unsigned bnd = (rr < N_NODES) ? rstart[rr] : (unsigned)N_EDGES;
        sb[i] = (unsigned)__builtin_amdgcn_readfirstlane((int)bnd);
    }

#pragma unroll
    for (int r = 0; r < 4; ++r) {
        const int row = rowBase + r;
        const unsigned s = sb[r];
        const unsigned e = sb[r + 1];
        const unsigned n = e - s;
        const unsigned nfull = n >> 3;    // full 8-edge batches

        float ax = 0.f, ay = 0.f, bx = 0.f, by = 0.f;

        int2 E0[8], E1[8];
        unsigned g0[8], g1[8];

        auto LOADREC = [&](int2 (&E)[8], unsigned base) {
#pragma unroll
            for (int k = 0; k < 8; ++k) E[k] = rec[base + k];
        };
        auto GATHER = [&](unsigned (&g)[8], const int2 (&E)[8]) {
#pragma unroll
            for (int k = 0; k < 8; ++k)
                g[k] = h16[(size_t)(((unsigned)E[k].x) & 0x1FFFFu) * 64 + lane];
        };
        auto FMA8 = [&](const int2 (&E)[8], const unsigned (&g)[8]) {
#pragma unroll
            for (int k = 0; k < 8; ++k) {
                const float v = __int_as_float(E[k].y);
                if (k & 1) {
                    bx = fmaf(v, __uint_as_float(g[k] << 16), bx);
                    by = fmaf(v, __uint_as_float(g[k] & 0xffff0000u), by);
                } else {
                    ax = fmaf(v, __uint_as_float(g[k] << 16), ax);
                    ay = fmaf(v, __uint_as_float(g[k] & 0xffff0000u), ay);
                }
            }
        };

        if (nfull) {
            LOADREC(E0, s);
            GATHER(g0, E0);
            unsigned bi = 1;
            for (; bi + 1 < nfull; bi += 2) {
                LOADREC(E1, s + bi * 8);
                GATHER(g1, E1);
                FMA8(E0, g0);
                LOADREC(E0, s + (bi + 1) * 8);
                GATHER(g0, E0);
                FMA8(E1, g1);
            }
            if (bi < nfull) {
                LOADREC(E1, s + bi * 8);
                GATHER(g1, E1);
                FMA8(E0, g0);
                FMA8(E1, g1);
            } else {
                FMA8(E0, g0);
            }
        }

        // masked tail batch (n & 7 edges)
        const unsigned tn = n & 7;
        if (tn) {
            const unsigned tb = s + nfull * 8;
            int2 Et[8];
            unsigned gt[8];
#pragma unroll
            for (int k = 0; k < 8; ++k) {
                const unsigned idx = tb + (unsigned)k;
                Et[k] = rec[idx < e ? idx : e - 1u];
            }
#pragma unroll
            for (int k = 0; k < 8; ++k)
                gt[k] = h16[(size_t)(((unsigned)Et[k].x) & 0x1FFFFu) * 64 + lane];
#pragma unroll
            for (int k = 0; k < 8; ++k) {
                const float v = (tb + (unsigned)k < e) ? __int_as_float(Et[k].y) : 0.f;
                if (k & 1) {
                    bx = fmaf(v, __uint_as_float(gt[k] << 16), bx);
                    by = fmaf(v, __uint_as_float(gt[k] & 0xffff0000u), by);
                } else {
                    ax = fmaf(v, __uint_as_float(gt[k] << 16), ax);
                    ay = fmaf(v, __uint_as_float(gt[k] & 0xffff0000u), ay);
                }
            }
        }

        // epilogue: out = selu(h*skip + Ah + bias), lane owns cols c2, c2+1
        const unsigned hw = h16[(size_t)row * 64 + lane];
        float ox = fmaf(__uint_as_float(hw << 16),         sk.x, (ax + bx) + bs.x);
        float oy = fmaf(__uint_as_float(hw & 0xffff0000u), sk.y, (ay + by) + bs.y);
        ox = selu_f(ox);
        oy = selu_f(oy);
        f32x2_t o;
        o.x = ox;
        o.y = oy;
        __builtin_nontemporal_store(o, (f32x2_t*)&out[(size_t)row * D + c2]);
    }
}

// ---------------- Fallback path (atomic COO, all fp32) -----------------------
__global__ __launch_bounds__(256) void gemm_fb_kernel(
    const float* __restrict__ feat, const float* __restrict__ W,
    const float* __restrict__ bias, const float* __restrict__ skip,
    float* __restrict__ h, float* __restrict__ out)
{
    __shared__ float Wl[D * D];
    __shared__ float Fl[32 * D];
    const int tid = threadIdx.x;

    const float4* W4 = (const float4*)W;
    float4* Wl4 = (float4*)Wl;
#pragma unroll
    for (int i = 0; i < 16; ++i) Wl4[tid + 256 * i] = W4[tid + 256 * i];

    const size_t rowBase = (size_t)blockIdx.x * 32;
    const float4* F4 = (const float4*)(feat + rowBase * D);
    float4* Fl4 = (float4*)Fl;
#pragma unroll
    for (int i = 0; i < 4; ++i) Fl4[tid + 256 * i] = F4[tid + 256 * i];
    __syncthreads();

    const int colg = (tid & 31) * 4;
    const int row0 = (tid >> 5) * 4;
    float4 acc[4];
#pragma unroll
    for (int r = 0; r < 4; ++r) acc[r] = make_float4(0.f, 0.f, 0.f, 0.f);
#pragma unroll 4
    for (int k = 0; k < D; ++k) {
        const float4 w = *(const float4*)&Wl[k * D + colg];
#pragma unroll
        for (int r = 0; r < 4; ++r) {
            const float aa = Fl[(row0 + r) * D + k];
            acc[r].x += aa * w.x; acc[r].y += aa * w.y;
            acc[r].z += aa * w.z; acc[r].w += aa * w.w;
        }
    }
    const float4 sk = *(const float4*)&skip[colg];
    const float4 bs = *(const float4*)&bias[colg];
#pragma unroll
    for (int r = 0; r < 4; ++r) {
        const size_t row = rowBase + row0 + r;
        *(float4*)&h[row * D + colg] = acc[r];
        float4 o;
        o.x = acc[r].x * sk.x + bs.x; o.y = acc[r].y * sk.y + bs.y;
        o.z = acc[r].z * sk.z + bs.z; o.w = acc[r].w * sk.w + bs.w;
        *(float4*)&out[row * D + colg] = o;
    }
}

__global__ __launch_bounds__(256) void spmm_atomic_kernel(
    const int* __restrict__ erow, const int* __restrict__ ecol,
    const float* __restrict__ eval_, const float* __restrict__ h,
    float* __restrict__ out)
{
    const int e = blockIdx.x * 4 + (threadIdx.x >> 6);
    if (e >= N_EDGES) return;
    const int lane = threadIdx.x & 63;
    const int r = erow[e];
    const int c = ecol[e];
    const float v = eval_[e];
    const float2 hv = *(const float2*)&h[(size_t)c * D + lane * 2];
    float* o = &out[(size_t)r * D + lane * 2];
    atomicAdd(o + 0, v * hv.x);
    atomicAdd(o + 1, v * hv.y);
}

__global__ __launch_bounds__(256) void selu_kernel(float* __restrict__ out)
{
    const size_t i = (size_t)blockIdx.x * blockDim.x + threadIdx.x;
    float4 v = ((float4*)out)[i];
    v.x = selu_f(v.x); v.y = selu_f(v.y); v.z = selu_f(v.z); v.w = selu_f(v.w);
    ((float4*)out)[i] = v;
}

extern "C" void kernel_launch(void* const* d_in, const int* in_sizes, int n_in,
                              void* d_out, int out_size, void* d_ws, size_t ws_size,
                              hipStream_t stream)
{
    const float* feat  = (const float*)d_in[0];
    const int*   erow  = (const int*)d_in[1];
    const int*   ecol  = (const int*)d_in[2];
    const float* eval_ = (const float*)d_in[3];
    const float* W     = (const float*)d_in[4];
    const float* bias  = (const float*)d_in[5];
    const float* skip  = (const float*)d_in[6];

    float* out = (float*)d_out;

    // fast-path workspace layout (bytes) — identical to R4's proven layout
    const size_t off_h16  = 0;            // 25,600,000
    const size_t off_tbl  = 25600000;     //    782,000
    const size_t off_lex  = 26382000;     //    782,336
    const size_t off_bs   = 27164336;     //      1,024
    const size_t off_rst  = 27165360;     //    400,000
    const size_t off_wt   = 27565360;     //     32,768
    const size_t off_rec  = 27598128;     // 12,800,000
    const size_t off_rec2 = 40398128;     // 12,800,000
    const size_t needed   = 53198128;

    char* ws = (char*)d_ws;
    unsigned*       h16    = (unsigned*)(ws + off_h16);
    unsigned*       tbl    = (unsigned*)(ws + off_tbl);
    unsigned*       lex    = (unsigned*)(ws + off_lex);
    unsigned*       bsum   = (unsigned*)(ws + off_bs);
    unsigned*       rstart = (unsigned*)(ws + off_rst);
    unsigned short* wt     = (unsigned short*)(ws + off_wt);
    int2*           rec    = (int2*)(ws + off_rec);
    int2*           rec2   = (int2*)(ws + off_rec2);

    if (ws_size >= needed) {
        bhist_prep_kernel<<<EB + 4, 256, 0, stream>>>(erow, W, tbl, wt);
        scan_local_kernel<<<SCAN_BLKS, 1024, 0, stream>>>(tbl, lex, bsum);
        bscatter_kernel<<<EB, 256, 0, stream>>>(erow, ecol, eval_, lex, bsum, tbl, rec);
        gemm_bsort_kernel<<<GEMM_BLKS + NB, 256, 0, stream>>>(
            feat, wt, h16, tbl, rec, rec2, rstart);
        spmm_csr_kernel<<<SPMM_BLKS, 256, 0, stream>>>(
            rstart, rec2, h16, skip, bias, out);
    } else {
        float* h = (float*)d_ws;
        gemm_fb_kernel<<<N_NODES / 32, 256, 0, stream>>>(feat, W, bias, skip, h, out);
        spmm_atomic_kernel<<<N_EDGES / 4, 256, 0, stream>>>(erow, ecol, eval_, h, out);
        selu_kernel<<<(N_NODES * D) / (256 * 4), 256, 0, stream>>>(out);
    }
}